// Round 7
// baseline (556472.803 us; speedup 1.0000x reference)
//
#include <hip/hip_runtime.h>
#include <stdint.h>

#define T_STEPS 4096
#define BATCH 32
#define HID 512
#define GROUPS 8            // blocks per batch
#define BLK_THREADS 1024    // 16 waves; 256 blocks = exactly 1/CU
#define NBLOCKS 256

typedef _Float16 h2_t __attribute__((ext_vector_type(2)));

__device__ inline uint32_t pack_h2(float a, float b) {
  h2_t v;
  v.x = (_Float16)a;
  v.y = (_Float16)b;
  return __builtin_bit_cast(uint32_t, v);
}

__device__ inline float fdot2(uint32_t a, uint32_t b, float c) {
  return __builtin_amdgcn_fdot2(__builtin_bit_cast(h2_t, a),
                                __builtin_bit_cast(h2_t, b), c, false);
}

// AGPR-resident weight read (unified RF; proven rounds 3-6 to keep W_hh
// on-chip: FETCH_SIZE ~94 MB = one-time traffic only).
__device__ inline uint32_t aread(uint32_t a) {
  uint32_t v;
  asm("v_accvgpr_read_b32 %0, %1" : "=v"(v) : "a"(a));
  return v;
}

// L2-scope ops (sc0: bypass L1, served by the XCD's own L2 — valid because
// the claim protocol guarantees all 8 groups of a batch are same-XCD).
__device__ inline uint32_t l2_load_u32(const uint32_t* p) {
  uint32_t v;
  asm volatile("global_load_dword %0, %1, off sc0\n\ts_waitcnt vmcnt(0)"
               : "=v"(v) : "v"(p) : "memory");
  return v;
}
__device__ inline void l2_store_u32(uint32_t* p, uint32_t v) {
  asm volatile("global_store_dword %0, %1, off sc0" :: "v"(p), "v"(v)
               : "memory");
}
__device__ inline void waitcnt_vm0() {
  asm volatile("s_waitcnt vmcnt(0)" ::: "memory");
}

__device__ inline float sigf(float x) { return 1.0f / (1.0f + __expf(-x)); }
__device__ inline float tanh_fast(float x) {
  float a = fabsf(x);
  float e = __expf(-2.0f * a);
  float r = (1.0f - e) / (1.0f + e);
  return copysignf(r, x);
}

// Round 7 = round 6's XCD-claim + sc0/L2-local comms, with the protocol
// depressurized and the gacc race fixed:
//
// SYNC: producer stores its 32 packed-f16x2 h dwords (sc0), drains with
// s_waitcnt vmcnt(0), then stores a per-group step counter (sc0). Each
// consumer wave needs exactly ONE group's slice (cols 64*cs..64*cs+63 ==
// group cs's units), so it polls ONE uniform counter dword — a single
// broadcast L2 request per wave per poll iteration, with s_sleep(1)
// backoff. Round-6 failure mode (64-lane tagged-data polls from 512
// waves/XCD with no backoff -> L2 queue congestion -> metastable slow
// mode) is structurally removed: poll traffic drops ~300x.
//
// RACE FIX: gacc[sl] is now zeroed by the activation wave itself AFTER it
// reads the sums (program order + the next step's barrier make this safe
// for the next use at t+2). The old cross-wave "zero the other parity
// slot" could clobber gacc while the activation wave was still reading it.
__global__ __launch_bounds__(BLK_THREADS)
void lstm_xcd(const float* __restrict__ x0,
              const float* __restrict__ W_ih,
              const float* __restrict__ W_hh,
              const float* __restrict__ b_ih,
              const float* __restrict__ b_hh,
              const float* __restrict__ W_lin,
              const float* __restrict__ b_lin,
              float* __restrict__ y,
              uint32_t* __restrict__ h_ex,   // [2][BATCH][256] packed f16x2
              uint32_t* __restrict__ cnt,    // [BATCH][16] step counters
              int* __restrict__ claim)       // [8][16] per-XCD claim ctrs
{
  __shared__ float x0_lds[T_STEPS];     // 16 KB: this batch's x0 column
  __shared__ float ylds[T_STEPS];       // 16 KB: per-block y partials
  __shared__ uint32_t trans[16][32];    // per-wave packed-h staging
  __shared__ float gacc[2][256];        // parity-buffered gate accumulators
  __shared__ int s_bg;

  const int tid = threadIdx.x;

  // ---- claim a (batch, group) slot on THIS block's physical XCD ----
  if (tid == 0) {
    uint32_t xcc;
    asm volatile("s_getreg_b32 %0, hwreg(HW_REG_XCC_ID)" : "=s"(xcc));
    xcc &= 7;
    int slot = atomicAdd(claim + xcc * 16, 1);   // agent-scope, one-time
    s_bg = (slot < 32) ? (int)(((4 * xcc + (slot >> 3)) << 3) | (slot & 7))
                       : -1;
  }
  __syncthreads();
  if (s_bg < 0) return;                  // surplus block
  const int b  = s_bg >> 3;              // batch (same XCD for all 8 groups)
  const int g  = s_bg & 7;               // group within batch
  const int u0 = g * 64;                 // first hidden unit owned
  const int wv = tid >> 6;               // wave 0..15
  const int rg = wv >> 3;                // row-group 0..1
  const int cs = wv & 7;                 // col-slice 0..7 == producer group
  const int l  = tid & 63;

  // ---- one-time: W_hh slice -> packed f16x2 -> AGPRs ----
  uint32_t a0[32], a1[32];
  {
    const int r0 = 128 * rg + l;
    const int r1 = r0 + 64;
    const int R0 = (r0 >> 6) * HID + u0 + (r0 & 63);  // gate*512 + unit
    const int R1 = (r1 >> 6) * HID + u0 + (r1 & 63);
    const float2* p0 = (const float2*)(W_hh + (size_t)R0 * HID + 64 * cs);
    const float2* p1 = (const float2*)(W_hh + (size_t)R1 * HID + 64 * cs);
#pragma unroll
    for (int k = 0; k < 32; ++k) {
      float2 a = p0[k], c = p1[k];
      uint32_t t0 = pack_h2(a.x, a.y);
      uint32_t t1 = pack_h2(c.x, c.y);
      asm("v_accvgpr_write_b32 %0, %1" : "=a"(a0[k]) : "v"(t0));
      asm("v_accvgpr_write_b32 %0, %1" : "=a"(a1[k]) : "v"(t1));
    }
  }
  // ---- one-time: x0 column, y partials, gacc ----
  for (int i = tid; i < T_STEPS; i += BLK_THREADS) {
    x0_lds[i] = x0[i * BATCH + b];
    ylds[i] = 0.f;
  }
  if (tid < 256) { gacc[0][tid] = 0.f; gacc[1][tid] = 0.f; }

  // ---- activation-lane constants (lanes 0..63 of wave 0) ----
  float c_state = 0.f;
  float wih_[4] = {0.f, 0.f, 0.f, 0.f}, bs_[4] = {0.f, 0.f, 0.f, 0.f};
  float wlin_u = 0.f, blin = 0.f;
  if (tid < 64) {
#pragma unroll
    for (int j = 0; j < 4; ++j) {
      int R = j * HID + u0 + tid;
      wih_[j] = W_ih[R];
      bs_[j] = b_ih[R] + b_hh[R];
    }
    wlin_u = W_lin[u0 + tid];
    blin = b_lin[0];
  }

  // ---- pointers: h slots (parity), own counter line ----
  uint32_t* hslot[2] = { h_ex + ((size_t)0 * BATCH + b) * 256,
                         h_ex + ((size_t)1 * BATCH + b) * 256 };
  uint32_t* cnt_b = cnt + b * 16;
  const uint32_t* cw = cnt_b + cs;       // wave-uniform poll address

  __syncthreads();

  int dead = 0;
  for (int t = 0; t < T_STEPS; ++t) {
    const int sl = t & 1, ns = sl ^ 1;

    // ---- poll producer cs's counter (one uniform dword, backoff) ----
    {
      int guard = 0;
      for (;;) {
        uint32_t c = l2_load_u32(cw);
        if ((int)c >= t) break;
        if (dead || ++guard > (1 << 20)) { dead = 1; break; }  // anti-hang
        __builtin_amdgcn_s_sleep(1);
      }
    }
    // ---- load own 32-dword packed slice; stage to LDS for broadcast ----
    if (l < 32) {
      uint32_t v = l2_load_u32(hslot[sl] + 32 * cs + l);
      trans[wv][l] = v;
    }
    // ---- matvec: 2 rows x 64 cols per lane, fp32 accumulate ----
    float acc0 = 0.f, acc1 = 0.f;
    const uint4* hp = (const uint4*)trans[wv];   // wave-uniform broadcast
#pragma unroll
    for (int q = 0; q < 8; ++q) {
      uint4 h4 = hp[q];
      const int k = 4 * q;
      acc0 = fdot2(aread(a0[k + 0]), h4.x, acc0); acc1 = fdot2(aread(a1[k + 0]), h4.x, acc1);
      acc0 = fdot2(aread(a0[k + 1]), h4.y, acc0); acc1 = fdot2(aread(a1[k + 1]), h4.y, acc1);
      acc0 = fdot2(aread(a0[k + 2]), h4.z, acc0); acc1 = fdot2(aread(a1[k + 2]), h4.z, acc1);
      acc0 = fdot2(aread(a0[k + 3]), h4.w, acc0); acc1 = fdot2(aread(a1[k + 3]), h4.w, acc1);
    }
    atomicAdd(&gacc[sl][128 * rg + l], acc0);       // 2-way bank, conflict-free
    atomicAdd(&gacc[sl][128 * rg + 64 + l], acc1);
    __syncthreads();   // the ONE block barrier per step

    // ---- activations + publish (wave 0, 64 lanes = 64 owned units) ----
    if (tid < 64) {
      const float xv = x0_lds[t];
      float s0 = gacc[sl][tid];
      float s1 = gacc[sl][tid + 64];
      float s2 = gacc[sl][tid + 128];
      float s3 = gacc[sl][tid + 192];
      float gi = s0 + xv * wih_[0] + bs_[0];
      float gf = s1 + xv * wih_[1] + bs_[1];
      float gg = s2 + xv * wih_[2] + bs_[2];
      float go = s3 + xv * wih_[3] + bs_[3];
      float si = sigf(gi), sf = sigf(gf), tg_ = tanh_fast(gg), so = sigf(go);
      c_state = sf * c_state + si * tg_;
      float h = so * tanh_fast(c_state);

      // publish: packed f16x2 pairs (32 dwords, one coalesced store) ...
      float hn = __shfl_down(h, 1, 64);
      if ((tid & 1) == 0)
        l2_store_u32(hslot[ns] + 32 * g + (tid >> 1), pack_h2(h, hn));
      // ... drain, then the counter store (the "release")
      waitcnt_vm0();
      if (tid == 0) l2_store_u32(cnt_b + g, (uint32_t)(t + 1));

      // recycle gacc[sl] for step t+2: safe by program order — any wave of
      // this block adding into gacc[sl] at t+2 must first pass the t+1
      // barrier, which this wave only reaches after these writes.
      gacc[sl][tid] = 0.f;
      gacc[sl][tid + 64] = 0.f;
      gacc[sl][tid + 128] = 0.f;
      gacc[sl][tid + 192] = 0.f;

      // y partial (off critical path): fold 64 units -> ylds[t]
      float p = wlin_u * h;
#pragma unroll
      for (int m = 32; m >= 1; m >>= 1) p += __shfl_xor(p, m, 64);
      if (tid == 0) ylds[t] = p;
    }
  }

  // ---- drain: block partials -> global y (g==0 adds bias + residual) ----
  __syncthreads();
  for (int i = tid; i < T_STEPS; i += BLK_THREADS) {
    float val = ylds[i];
    if (g == 0) val += blin + x0_lds[i];
    unsafeAtomicAdd(&y[i * BATCH + b], val);
  }
}

extern "C" void kernel_launch(void* const* d_in, const int* in_sizes, int n_in,
                              void* d_out, int out_size, void* d_ws, size_t ws_size,
                              hipStream_t stream) {
  const float* x0    = (const float*)d_in[0];
  const float* W_ih  = (const float*)d_in[1];
  const float* W_hh  = (const float*)d_in[2];
  const float* b_ih  = (const float*)d_in[3];
  const float* b_hh  = (const float*)d_in[4];
  const float* W_lin = (const float*)d_in[5];
  const float* b_lin = (const float*)d_in[6];
  float* y = (float*)d_out;

  uint32_t* h_ex = (uint32_t*)d_ws;                         // 64 KB
  uint32_t* cnt  = h_ex + 2 * BATCH * 256;                  // 2 KB
  int* claim     = (int*)(cnt + BATCH * 16);                // 512 B
  const size_t init_bytes = (2 * BATCH * 256 + BATCH * 16) * sizeof(uint32_t)
                            + 8 * 16 * sizeof(int);

  // memset 0: slot-0 h = 0 packed f16x2 == h0 state; counters = 0 means
  // "h_0 available"; claim = 0.
  hipMemsetAsync(d_ws, 0, init_bytes, stream);
  hipMemsetAsync(d_out, 0, (size_t)out_size * sizeof(float), stream);

  hipLaunchKernelGGL(lstm_xcd, dim3(NBLOCKS), dim3(BLK_THREADS), 0, stream,
                     x0, W_ih, W_hh, b_ih, b_hh, W_lin, b_lin, y, h_ex, cnt,
                     claim);
}

// Round 9
// 14968.840 us; speedup vs baseline: 37.1754x; 37.1754x over previous
//
#include <hip/hip_runtime.h>
#include <stdint.h>

#define T_STEPS 4096
#define BATCH 32
#define HID 512
#define GROUPS 8            // blocks per batch
#define BLK_THREADS 1024    // 16 waves; 256 blocks = exactly 1/CU
#define NBLOCKS 256

typedef _Float16 h2_t __attribute__((ext_vector_type(2)));
typedef uint32_t u32x16 __attribute__((ext_vector_type(16)));

__device__ inline uint32_t pack_h2(float a, float b) {
  h2_t v;
  v.x = (_Float16)a;
  v.y = (_Float16)b;
  return __builtin_bit_cast(uint32_t, v);
}

__device__ inline float fdot2(uint32_t a, uint32_t b, float c) {
  return __builtin_amdgcn_fdot2(__builtin_bit_cast(h2_t, a),
                                __builtin_bit_cast(h2_t, b), c, false);
}

// AGPR-resident weight read (unified RF; proven rounds 3-7: FETCH_SIZE
// ~95 MB == one-time traffic only, no per-step weight re-fetch).
__device__ inline uint32_t aread(uint32_t a) {
  uint32_t v;
  asm("v_accvgpr_read_b32 %0, %1" : "=v"(v) : "a"(a));
  return v;
}

// Launder a wave-uniform pointer into an SGPR-resident uint64 so the "s"
// inline-asm constraint can bind it (round-8 compile failure: address chain
// through LDS-read s_bg defeats divergence analysis -> compiler bound the
// pointer to a VGPR pair, which s_load_* cannot take).
__device__ inline uint64_t uni64(const void* p) {
  uint32_t lo = __builtin_amdgcn_readfirstlane((uint32_t)(uintptr_t)p);
  uint32_t hi = __builtin_amdgcn_readfirstlane((uint32_t)((uintptr_t)p >> 32));
  return ((uint64_t)hi << 32) | lo;
}

// SCALAR-PATH communication. Round 6/7 bug: sc0 vector loads do NOT bypass
// vL1 on gfx950 (sc0 = workgroup-scope bit), so polls spun on stale L1
// lines and data reads were silently stale (absmax 0.047). The scalar K$
// CAN be invalidated in one instruction: s_dcache_inv -> next s_load misses
// K$ -> served fresh from the XCD's L2 (same-XCD guaranteed by the claim
// protocol). h is wave-uniform, so SMEM is also the natural data path:
// 2x s_load_dwordx16 pulls the whole 32-dword slice into SGPRs feeding
// v_dot2 src1 directly — no per-lane loads, no LDS transpose.
__device__ inline void kinv() {
  asm volatile("s_dcache_inv" ::: "memory");
}
__device__ inline uint32_t sload1(uint64_t p) {
  uint32_t v;
  asm volatile("s_load_dword %0, %1, 0x0\n\ts_waitcnt lgkmcnt(0)"
               : "=s"(v) : "s"(p) : "memory");
  return v;
}
__device__ inline u32x16 sload16(uint64_t p) {
  u32x16 v;
  asm volatile("s_load_dwordx16 %0, %1, 0x0\n\ts_waitcnt lgkmcnt(0)"
               : "=s"(v) : "s"(p) : "memory");
  return v;
}
__device__ inline void waitcnt_vm0() {
  asm volatile("s_waitcnt vmcnt(0)" ::: "memory");
}

__device__ inline float sigf(float x) { return 1.0f / (1.0f + __expf(-x)); }
__device__ inline float tanh_fast(float x) {
  float a = fabsf(x);
  float e = __expf(-2.0f * a);
  float r = (1.0f - e) / (1.0f + e);
  return copysignf(r, x);
}

// Round 9 = round 8 with the inline-asm operand fix. Structure: XCD-claimed
// placement (the XCD's L2 is the legal coherence point) + scalar-path
// sync/data. Producer: 32 packed-f16x2 plain stores (vL1 write-through ->
// L2), s_waitcnt vmcnt(0), plain counter store. Consumer wave:
// { s_dcache_inv; s_load counter } poll with s_sleep backoff, then
// s_load_dwordx16 x2 of its producer-group's slice (covered by the same
// inv). Parity-buffer overwrite safety: a block publishes step t+2 only
// after passing the t+1 barrier, which requires all its waves to have
// consumed slot[(t+1)&1] — and its own consumption implies (via the
// counters) every other block reached t+1 too.
__global__ __launch_bounds__(BLK_THREADS)
void lstm_smem(const float* __restrict__ x0,
               const float* __restrict__ W_ih,
               const float* __restrict__ W_hh,
               const float* __restrict__ b_ih,
               const float* __restrict__ b_hh,
               const float* __restrict__ W_lin,
               const float* __restrict__ b_lin,
               float* __restrict__ y,
               uint32_t* __restrict__ h_ex,   // [2][BATCH][256] packed f16x2
               uint32_t* __restrict__ cnt,    // [BATCH][16] counters (64B/b)
               int* __restrict__ claim)       // [8][16] per-XCD claim ctrs
{
  __shared__ float x0_lds[T_STEPS];     // 16 KB: this batch's x0 column
  __shared__ float ylds[T_STEPS];       // 16 KB: per-block y partials
  __shared__ float gacc[2][256];        // parity-buffered gate accumulators
  __shared__ int s_bg;

  const int tid = threadIdx.x;

  // ---- claim a (batch, group) slot on THIS block's physical XCD ----
  if (tid == 0) {
    uint32_t xcc;
    asm volatile("s_getreg_b32 %0, hwreg(HW_REG_XCC_ID)" : "=s"(xcc));
    xcc &= 7;
    int slot = atomicAdd(claim + xcc * 16, 1);   // agent-scope, one-time
    s_bg = (slot < 32) ? (int)(((4 * xcc + (slot >> 3)) << 3) | (slot & 7))
                       : -1;
  }
  __syncthreads();
  if (s_bg < 0) return;                  // surplus block
  const int b  = s_bg >> 3;              // batch (same XCD for all 8 groups)
  const int g  = s_bg & 7;               // group within batch
  const int u0 = g * 64;                 // first hidden unit owned
  const int wv = tid >> 6;               // wave 0..15
  const int rg = wv >> 3;                // row-group 0..1
  const int cs = wv & 7;                 // col-slice 0..7 == producer group
  const int l  = tid & 63;

  // ---- one-time: W_hh slice -> packed f16x2 -> AGPRs ----
  uint32_t a0[32], a1[32];
  {
    const int r0 = 128 * rg + l;
    const int r1 = r0 + 64;
    const int R0 = (r0 >> 6) * HID + u0 + (r0 & 63);  // gate*512 + unit
    const int R1 = (r1 >> 6) * HID + u0 + (r1 & 63);
    const float2* p0 = (const float2*)(W_hh + (size_t)R0 * HID + 64 * cs);
    const float2* p1 = (const float2*)(W_hh + (size_t)R1 * HID + 64 * cs);
#pragma unroll
    for (int k = 0; k < 32; ++k) {
      float2 a = p0[k], c = p1[k];
      uint32_t t0 = pack_h2(a.x, a.y);
      uint32_t t1 = pack_h2(c.x, c.y);
      asm("v_accvgpr_write_b32 %0, %1" : "=a"(a0[k]) : "v"(t0));
      asm("v_accvgpr_write_b32 %0, %1" : "=a"(a1[k]) : "v"(t1));
    }
  }
  // ---- one-time: x0 column, y partials, gacc ----
  for (int i = tid; i < T_STEPS; i += BLK_THREADS) {
    x0_lds[i] = x0[i * BATCH + b];
    ylds[i] = 0.f;
  }
  if (tid < 256) { gacc[0][tid] = 0.f; gacc[1][tid] = 0.f; }

  // ---- activation-lane constants (lanes 0..63 of wave 0) ----
  float c_state = 0.f;
  float wih_[4] = {0.f, 0.f, 0.f, 0.f}, bs_[4] = {0.f, 0.f, 0.f, 0.f};
  float wlin_u = 0.f, blin = 0.f;
  if (tid < 64) {
#pragma unroll
    for (int j = 0; j < 4; ++j) {
      int R = j * HID + u0 + tid;
      wih_[j] = W_ih[R];
      bs_[j] = b_ih[R] + b_hh[R];
    }
    wlin_u = W_lin[u0 + tid];
    blin = b_lin[0];
  }

  // ---- wave-uniform SGPR addresses (laundered via readfirstlane) ----
  uint32_t* hb = h_ex + (size_t)b * 256;            // parity stride: BATCH*256
  const uint64_t dpu[2] = { uni64(hb + 32 * cs),
                            uni64(hb + BATCH * 256 + 32 * cs) };
  const uint64_t cwu = uni64(cnt + b * 16 + cs);    // poll address
  uint32_t* pub01[2] = { hb + 32 * g, hb + BATCH * 256 + 32 * g };
  uint32_t* cnt_b = cnt + b * 16;

  __syncthreads();

  int dead = 0;
  for (int t = 0; t < T_STEPS; ++t) {
    const int sl = t & 1, ns = sl ^ 1;

    // ---- poll producer cs's counter via K$-inv + scalar load ----
    {
      int guard = 0;
      for (;;) {
        kinv();
        uint32_t c = sload1(cwu);
        if ((int)c >= t) break;
        if (dead || ++guard > (1 << 20)) { dead = 1; break; }  // anti-hang
        __builtin_amdgcn_s_sleep(1);
      }
    }
    // ---- fetch the 32-dword slice into SGPRs (fresh: covered by the inv) ----
    u32x16 hs0 = sload16(dpu[sl]);
    u32x16 hs1 = sload16(dpu[sl] + 64);

    // ---- matvec: 2 rows x 64 cols per lane; h uniform from SGPRs ----
    float acc0 = 0.f, acc1 = 0.f;
#pragma unroll
    for (int k = 0; k < 16; ++k) {
      acc0 = fdot2(aread(a0[k]), hs0[k], acc0);
      acc1 = fdot2(aread(a1[k]), hs0[k], acc1);
    }
#pragma unroll
    for (int k = 0; k < 16; ++k) {
      acc0 = fdot2(aread(a0[16 + k]), hs1[k], acc0);
      acc1 = fdot2(aread(a1[16 + k]), hs1[k], acc1);
    }
    atomicAdd(&gacc[sl][128 * rg + l], acc0);       // 2-way bank, conflict-free
    atomicAdd(&gacc[sl][128 * rg + 64 + l], acc1);
    __syncthreads();   // the ONE block barrier per step

    // ---- activations + publish (wave 0, 64 lanes = 64 owned units) ----
    if (tid < 64) {
      const float xv = x0_lds[t];
      float gi = gacc[sl][tid]       + xv * wih_[0] + bs_[0];
      float gf = gacc[sl][tid + 64]  + xv * wih_[1] + bs_[1];
      float gg = gacc[sl][tid + 128] + xv * wih_[2] + bs_[2];
      float go = gacc[sl][tid + 192] + xv * wih_[3] + bs_[3];
      float si = sigf(gi), sf = sigf(gf), tg_ = tanh_fast(gg), so = sigf(go);
      c_state = sf * c_state + si * tg_;
      float h = so * tanh_fast(c_state);

      // publish: packed f16x2 (32 dwords, one coalesced store) -> L2 ...
      float hn = __shfl_down(h, 1, 64);
      if ((tid & 1) == 0) pub01[ns][tid >> 1] = pack_h2(h, hn);
      // ... drain to L2, then the counter store (the "release")
      waitcnt_vm0();
      if (tid == 0) cnt_b[g] = (uint32_t)(t + 1);

      // recycle gacc[sl] for step t+2 (safe: program order + next barrier)
      gacc[sl][tid] = 0.f;
      gacc[sl][tid + 64] = 0.f;
      gacc[sl][tid + 128] = 0.f;
      gacc[sl][tid + 192] = 0.f;

      // y partial (off critical path): fold 64 units -> ylds[t]
      float p = wlin_u * h;
#pragma unroll
      for (int m = 32; m >= 1; m >>= 1) p += __shfl_xor(p, m, 64);
      if (tid == 0) ylds[t] = p;
    }
  }

  // ---- drain: block partials -> global y (g==0 adds bias + residual) ----
  __syncthreads();
  for (int i = tid; i < T_STEPS; i += BLK_THREADS) {
    float val = ylds[i];
    if (g == 0) val += blin + x0_lds[i];
    unsafeAtomicAdd(&y[i * BATCH + b], val);
  }
}

extern "C" void kernel_launch(void* const* d_in, const int* in_sizes, int n_in,
                              void* d_out, int out_size, void* d_ws, size_t ws_size,
                              hipStream_t stream) {
  const float* x0    = (const float*)d_in[0];
  const float* W_ih  = (const float*)d_in[1];
  const float* W_hh  = (const float*)d_in[2];
  const float* b_ih  = (const float*)d_in[3];
  const float* b_hh  = (const float*)d_in[4];
  const float* W_lin = (const float*)d_in[5];
  const float* b_lin = (const float*)d_in[6];
  float* y = (float*)d_out;

  uint32_t* h_ex = (uint32_t*)d_ws;                         // 64 KB
  uint32_t* cnt  = h_ex + 2 * BATCH * 256;                  // 2 KB
  int* claim     = (int*)(cnt + BATCH * 16);                // 512 B
  const size_t init_bytes = (2 * BATCH * 256 + BATCH * 16) * sizeof(uint32_t)
                            + 8 * 16 * sizeof(int);

  // memset 0: slot-0 h = 0 (== h0), counters = 0 ("h_0 available"), claim=0
  (void)hipMemsetAsync(d_ws, 0, init_bytes, stream);
  (void)hipMemsetAsync(d_out, 0, (size_t)out_size * sizeof(float), stream);

  hipLaunchKernelGGL(lstm_smem, dim3(NBLOCKS), dim3(BLK_THREADS), 0, stream,
                     x0, W_ih, W_hh, b_ih, b_hh, W_lin, b_lin, y, h_ex, cnt,
                     claim);
}